// Round 12
// baseline (99.557 us; speedup 1.0000x reference)
//
#include <hip/hip_runtime.h>
#include <hip/hip_bf16.h>

// ---- problem constants: B=128, D=1024, ADA=1024, R=8, 4*D*R=32768 ----

typedef __attribute__((ext_vector_type(8))) __bf16 bf16x8;
typedef __attribute__((ext_vector_type(8))) short short8v;
typedef __attribute__((ext_vector_type(4))) float f32x4;

__device__ __forceinline__ float gelu_exact(float v) {
    return 0.5f * v * (1.0f + erff(v * 0.7071067811865476f));
}
__device__ __forceinline__ unsigned short f2bf(float f) {
    union { float f; unsigned u; } c; c.f = f;
    return (unsigned short)((c.u + 0x7FFFu + ((c.u >> 16) & 1u)) >> 16);
}
__device__ __forceinline__ float bf2f(unsigned short u) {
    union { float f; unsigned u32; } c; c.u32 = ((unsigned)u) << 16; return c.f;
}

// ---------- LayerNorm(ada_emb) -> c_bf16 ; cast x -> x_bf16 ; zero cnt1 ----------
__global__ __launch_bounds__(256) void ln_cast_kernel(
    const float* __restrict__ ada, const float* __restrict__ g, const float* __restrict__ be,
    const float* __restrict__ x, unsigned short* __restrict__ cbf, unsigned short* __restrict__ xbf,
    int* __restrict__ cnt1)
{
    int b = blockIdx.x, t = threadIdx.x;
    if (b < 16 && t == 0) cnt1[b] = 0;
    float4 v = ((const float4*)(ada + b * 1024))[t];
    float s  = v.x + v.y + v.z + v.w;
    float ss = v.x*v.x + v.y*v.y + v.z*v.z + v.w*v.w;
    #pragma unroll
    for (int off = 32; off; off >>= 1) { s += __shfl_xor(s, off); ss += __shfl_xor(ss, off); }
    __shared__ float rs[4], rss[4];
    int wid = t >> 6;
    if ((t & 63) == 0) { rs[wid] = s; rss[wid] = ss; }
    __syncthreads();
    float S  = rs[0] + rs[1] + rs[2] + rs[3];
    float SS = rss[0] + rss[1] + rss[2] + rss[3];
    float mu = S * (1.0f / 1024.0f);
    float rstd = rsqrtf(SS * (1.0f / 1024.0f) - mu * mu + 1e-5f);
    float4 gv = ((const float4*)g)[t];
    float4 bv = ((const float4*)be)[t];
    ushort4 o;
    o.x = f2bf((v.x - mu) * rstd * gv.x + bv.x);
    o.y = f2bf((v.y - mu) * rstd * gv.y + bv.y);
    o.z = f2bf((v.z - mu) * rstd * gv.z + bv.z);
    o.w = f2bf((v.w - mu) * rstd * gv.w + bv.w);
    ((ushort4*)(cbf + b * 1024))[t] = o;
    float4 xv = ((const float4*)(x + b * 1024))[t];
    ushort4 xo;
    xo.x = f2bf(xv.x); xo.y = f2bf(xv.y); xo.z = f2bf(xv.z); xo.w = f2bf(xv.w);
    ((ushort4*)(xbf + b * 1024))[t] = xo;
}

// ---------- MFMA GEMM body (round-3 staging/pipeline): C16 = bf16(A*B [+ bias]) ----------
// BT=false: B[k][n] row-major (ld=ldb).  BT=true: B[k][n] = Bsrc[n][k]
template <bool BT, bool BIAS>
__device__ __forceinline__ void gemm_body(
    const unsigned short* __restrict__ A, const float* __restrict__ Bm,
    unsigned short* __restrict__ C16, const float* __restrict__ bias,
    const int ldb, const int ldc, const int kchunk, const int k0base, const int n0)
{
    __shared__ __align__(16) unsigned short As[2][128 * 72];
    __shared__ __align__(16) unsigned short Bs[2][64 * 72];
    const int t = threadIdx.x;
    const int lane = t & 63, wid = t >> 6;
    const int wm = wid >> 1, wn = wid & 1;
    const int q = lane >> 4, c16 = lane & 15;

    const int arow = t >> 1, ahalf = t & 1;
    const unsigned short* aptr = A + arow * 1024 + k0base + ahalf * 32;
    const int adoff = arow * 72 + ahalf * 32;

    const int bnp = t & 31, bkc = t >> 5;   // !BT
    const int bnr = t >> 2, bpart = t & 3;  // BT
    const float* bptr = BT ? (Bm + (size_t)(n0 + bnr) * ldb + k0base + bpart * 16)
                           : (Bm + (size_t)(k0base + bkc * 8) * ldb + n0 + bnp * 2);

    f32x4 acc[4][2] = {};
    short8v ra0, ra1, ra2, ra3;
    float2 rb0, rb1, rb2, rb3, rb4, rb5, rb6, rb7;
    float4 rt0, rt1, rt2, rt3;

    auto LOAD = [&](int kk) {
        const int koff = kk << 6;
        const unsigned short* ap = aptr + koff;
        ra0 = *(const short8v*)(ap);      ra1 = *(const short8v*)(ap + 8);
        ra2 = *(const short8v*)(ap + 16); ra3 = *(const short8v*)(ap + 24);
        if (!BT) {
            const float* bp = bptr + (size_t)koff * ldb;
            rb0 = *(const float2*)(bp);                    rb1 = *(const float2*)(bp + (size_t)ldb);
            rb2 = *(const float2*)(bp + (size_t)2 * ldb);  rb3 = *(const float2*)(bp + (size_t)3 * ldb);
            rb4 = *(const float2*)(bp + (size_t)4 * ldb);  rb5 = *(const float2*)(bp + (size_t)5 * ldb);
            rb6 = *(const float2*)(bp + (size_t)6 * ldb);  rb7 = *(const float2*)(bp + (size_t)7 * ldb);
        } else {
            const float* bp = bptr + koff;
            rt0 = *(const float4*)(bp);     rt1 = *(const float4*)(bp + 4);
            rt2 = *(const float4*)(bp + 8); rt3 = *(const float4*)(bp + 12);
        }
    };
    auto STORE_LDS = [&](int buf) {
        unsigned short* ad = &As[buf][adoff];
        *(short8v*)(ad)      = ra0; *(short8v*)(ad + 8)  = ra1;
        *(short8v*)(ad + 16) = ra2; *(short8v*)(ad + 24) = ra3;
        if (!BT) {
            short8v s0, s1;
            s0[0]=(short)f2bf(rb0.x); s1[0]=(short)f2bf(rb0.y);
            s0[1]=(short)f2bf(rb1.x); s1[1]=(short)f2bf(rb1.y);
            s0[2]=(short)f2bf(rb2.x); s1[2]=(short)f2bf(rb2.y);
            s0[3]=(short)f2bf(rb3.x); s1[3]=(short)f2bf(rb3.y);
            s0[4]=(short)f2bf(rb4.x); s1[4]=(short)f2bf(rb4.y);
            s0[5]=(short)f2bf(rb5.x); s1[5]=(short)f2bf(rb5.y);
            s0[6]=(short)f2bf(rb6.x); s1[6]=(short)f2bf(rb6.y);
            s0[7]=(short)f2bf(rb7.x); s1[7]=(short)f2bf(rb7.y);
            *(short8v*)(&Bs[buf][(bnp * 2 + 0) * 72 + bkc * 8]) = s0;
            *(short8v*)(&Bs[buf][(bnp * 2 + 1) * 72 + bkc * 8]) = s1;
        } else {
            short8v s0, s1;
            s0[0]=(short)f2bf(rt0.x); s0[1]=(short)f2bf(rt0.y); s0[2]=(short)f2bf(rt0.z); s0[3]=(short)f2bf(rt0.w);
            s0[4]=(short)f2bf(rt1.x); s0[5]=(short)f2bf(rt1.y); s0[6]=(short)f2bf(rt1.z); s0[7]=(short)f2bf(rt1.w);
            s1[0]=(short)f2bf(rt2.x); s1[1]=(short)f2bf(rt2.y); s1[2]=(short)f2bf(rt2.z); s1[3]=(short)f2bf(rt2.w);
            s1[4]=(short)f2bf(rt3.x); s1[5]=(short)f2bf(rt3.y); s1[6]=(short)f2bf(rt3.z); s1[7]=(short)f2bf(rt3.w);
            *(short8v*)(&Bs[buf][bnr * 72 + bpart * 16])     = s0;
            *(short8v*)(&Bs[buf][bnr * 72 + bpart * 16 + 8]) = s1;
        }
    };

    const int nsteps = kchunk >> 6;
    LOAD(0);
    STORE_LDS(0);
    if (nsteps > 1) LOAD(1);
    __syncthreads();

    for (int kk = 0; kk < nsteps; ++kk) {
        if (kk + 1 < nsteps) STORE_LDS((kk + 1) & 1);
        if (kk + 2 < nsteps) LOAD(kk + 2);
        const unsigned short* Ab = &As[kk & 1][0];
        const unsigned short* Bb = &Bs[kk & 1][0];
        #pragma unroll
        for (int ks = 0; ks < 64; ks += 32) {
            bf16x8 af[4], bfv[2];
            #pragma unroll
            for (int mt = 0; mt < 4; ++mt)
                af[mt] = __builtin_bit_cast(bf16x8,
                    *(const short8v*)(Ab + (wm * 64 + mt * 16 + c16) * 72 + ks + q * 8));
            #pragma unroll
            for (int nt = 0; nt < 2; ++nt)
                bfv[nt] = __builtin_bit_cast(bf16x8,
                    *(const short8v*)(Bb + (wn * 32 + nt * 16 + c16) * 72 + ks + q * 8));
            #pragma unroll
            for (int mt = 0; mt < 4; ++mt)
                #pragma unroll
                for (int nt = 0; nt < 2; ++nt)
                    acc[mt][nt] = __builtin_amdgcn_mfma_f32_16x16x32_bf16(
                        af[mt], bfv[nt], acc[mt][nt], 0, 0, 0);
        }
        if (kk + 1 < nsteps) __syncthreads();
    }
    // store bf16 (D frag: col = lane&15, row = (lane>>4)*4 + j)
    #pragma unroll
    for (int mt = 0; mt < 4; ++mt) {
        const int m = wm * 64 + mt * 16 + q * 4;
        #pragma unroll
        for (int nt = 0; nt < 2; ++nt) {
            const int n = n0 + wn * 32 + nt * 16 + c16;
            const float bb = BIAS ? bias[n] : 0.0f;
            #pragma unroll
            for (int j = 0; j < 4; ++j)
                C16[(size_t)(m + j) * ldc + n] = f2bf(acc[mt][nt][j] + bb);
        }
    }
}

// arrive (release) + wait-all (acquire) on a per-tile counter; round-8-validated fencing
__device__ __forceinline__ void arrive_and_wait(int* cnt, int target, int t) {
    __syncthreads();                 // all slab stores issued & drained at barrier
    if (t == 0) {
        __threadfence();             // release: slab visible device-wide
        atomicAdd(cnt, 1);
        while (__hip_atomic_load(cnt, __ATOMIC_ACQUIRE, __HIP_MEMORY_SCOPE_AGENT) < target) {}
    }
    __syncthreads();
    __threadfence();                 // acquire for all threads
}

// ---- gemm13h: grid (16, 8, 2).
//  z=0: GEMM1 split-K8 -> P1b slab, then wide-tail: each block reduces its 1/8 of the tile -> hbf
//  z=1: GEMM3 split-K8 -> P2b slab
__global__ __launch_bounds__(256, 2) void gemm13h_kernel(
    const unsigned short* __restrict__ cbf, const float* __restrict__ W1, unsigned short* __restrict__ P1b,
    const unsigned short* __restrict__ xbf, const float* __restrict__ bdn, unsigned short* __restrict__ P2b,
    const float* __restrict__ b1, unsigned short* __restrict__ hbf, int* __restrict__ cnt1)
{
    const int nt = blockIdx.x, s = blockIdx.y, t = threadIdx.x;
    const bool g1 = blockIdx.z == 0;
    gemm_body<false, false>(g1 ? cbf : xbf, g1 ? W1 : bdn,
                            (g1 ? P1b : P2b) + s * 131072, nullptr,
                            1024, 1024, 128, s * 128, nt * 64);
    if (!g1) return;
    arrive_and_wait(&cnt1[nt], 8, t);
    // tail: rows [s*16, s*16+16), cols [nt*64, +64) ; ushort4 granularity
    const int row = s * 16 + (t >> 4);
    const int g4 = row * 256 + nt * 16 + (t & 15);   // ushort4 index into [128][1024]
    float4 acc = ((const float4*)b1)[nt * 16 + (t & 15)];
    #pragma unroll
    for (int p = 0; p < 8; ++p) {
        ushort4 v = ((const ushort4*)(P1b + p * 131072))[g4];
        acc.x += bf2f(v.x); acc.y += bf2f(v.y); acc.z += bf2f(v.z); acc.w += bf2f(v.w);
    }
    ushort4 o;
    o.x = f2bf(gelu_exact(acc.x));
    o.y = f2bf(gelu_exact(acc.y));
    o.z = f2bf(gelu_exact(acc.z));
    o.w = f2bf(gelu_exact(acc.w));
    ((ushort4*)hbf)[g4] = o;
}

// ---- GEMM2 (round-10 proven shape): wbf = bf16(hbf @ W2 + b2), 512 blocks ----
__global__ __launch_bounds__(256, 2) void gemm2_kernel(
    const unsigned short* __restrict__ hbf, const float* __restrict__ W2,
    const float* __restrict__ b2, unsigned short* __restrict__ wbf)
{
    gemm_body<false, true>(hbf, W2, wbf, b2, 32768, 32768, 1024, 0, blockIdx.x * 64);
}

// ---------- per-row epilogue: t2, y=gelu(.), ybf, t1 -> global ; zero cnt4 ----------
__device__ __forceinline__ void block_reduce8(float a[8], float* out8, float (*scr)[8], int t) {
    #pragma unroll
    for (int r = 0; r < 8; ++r)
        #pragma unroll
        for (int off = 32; off; off >>= 1)
            a[r] += __shfl_xor(a[r], off);
    if ((t & 63) == 0) {
        #pragma unroll
        for (int r = 0; r < 8; ++r) scr[t >> 6][r] = a[r];
    }
    __syncthreads();
    if (t < 8) out8[t] = scr[0][t] + scr[1][t] + scr[2][t] + scr[3][t];
    __syncthreads();
}

__global__ __launch_bounds__(256) void e1big_kernel(
    const unsigned short* __restrict__ P2b, const unsigned short* __restrict__ wbf,
    const float* __restrict__ x, unsigned short* __restrict__ ybf,
    float* __restrict__ t1g, int* __restrict__ cnt4)
{
    __shared__ float scr[4][8];
    __shared__ float t2s[8], t1s[8];
    const int b = blockIdx.x, t = threadIdx.x;
    if (b < 16 && t == 0) cnt4[b] = 0;
    const unsigned short* wrow = wbf + (size_t)b * 32768;
    const float* xrow = x + b * 1024;

    // stage 1: t2[r] = sum_d la2[b,d,r] * x[b,d]   (la2 = chunk 2 @ +16384)
    float a[8] = {0,0,0,0,0,0,0,0};
    #pragma unroll
    for (int i = 0; i < 4; ++i) {
        int d = t + i * 256;
        float xv = xrow[d];
        short8v wv = *(const short8v*)(wrow + 16384 + d * 8);
        #pragma unroll
        for (int r = 0; r < 8; ++r) a[r] += xv * bf2f((unsigned short)wv[r]);
    }
    block_reduce8(a, t2s, scr, t);
    float t2v[8];
    #pragma unroll
    for (int r = 0; r < 8; ++r) t2v[r] = t2s[r];

    // stage 2: y = gelu(sum P2b + lb2 @ t2); accumulate t1 = sum_l lb1[l,:]*y[l]
    float a1[8] = {0,0,0,0,0,0,0,0};
    #pragma unroll
    for (int i = 0; i < 4; ++i) {
        int l = t + i * 256;
        float s = 0.0f;
        #pragma unroll
        for (int p = 0; p < 8; ++p) s += bf2f(P2b[p * 131072 + b * 1024 + l]);
        short8v w2v = *(const short8v*)(wrow + 24576 + l * 8);
        #pragma unroll
        for (int r = 0; r < 8; ++r) s += bf2f((unsigned short)w2v[r]) * t2v[r];
        float y = gelu_exact(s);
        ybf[b * 1024 + l] = f2bf(y);
        short8v w1v = *(const short8v*)(wrow + 8192 + l * 8);
        #pragma unroll
        for (int r = 0; r < 8; ++r) a1[r] += y * bf2f((unsigned short)w1v[r]);
    }
    block_reduce8(a1, t1s, scr, t);
    if (t < 8) t1g[b * 8 + t] = t1s[t];
}

// ---- gemm4f: grid (16,16) split-K16 -> P1b slabs; wide-tail: out = x + la1@t1 + sum slabs ----
__global__ __launch_bounds__(256, 2) void gemm4f_kernel(
    const unsigned short* __restrict__ ybf, const float* __restrict__ bup,
    unsigned short* __restrict__ P1b, const unsigned short* __restrict__ wbf,
    const float* __restrict__ t1g, const float* __restrict__ x,
    float* __restrict__ out, int* __restrict__ cnt4)
{
    const int nt = blockIdx.x, s = blockIdx.y, t = threadIdx.x;
    gemm_body<true, false>(ybf, bup, P1b + s * 131072, nullptr,
                           1024, 1024, 64, s * 64, nt * 64);
    arrive_and_wait(&cnt4[nt], 16, t);
    // tail: rows [s*8, s*8+8), cols [nt*64, +64), 2 cols/thread
    const int row = s * 8 + (t >> 5);
    const int col = nt * 64 + (t & 31) * 2;
    const int idx = row * 1024 + col;
    float2 xv = *(const float2*)(x + idx);
    float s0 = xv.x, s1 = xv.y;
    #pragma unroll
    for (int p = 0; p < 16; ++p) {
        ushort2 v = *(const ushort2*)(P1b + p * 131072 + idx);
        s0 += bf2f(v.x); s1 += bf2f(v.y);
    }
    float t1v[8];
    #pragma unroll
    for (int r = 0; r < 8; ++r) t1v[r] = t1g[row * 8 + r];
    short8v w0 = *(const short8v*)(wbf + (size_t)row * 32768 + col * 8);
    short8v w1 = *(const short8v*)(wbf + (size_t)row * 32768 + (col + 1) * 8);
    #pragma unroll
    for (int r = 0; r < 8; ++r) {
        s0 += bf2f((unsigned short)w0[r]) * t1v[r];
        s1 += bf2f((unsigned short)w1[r]) * t1v[r];
    }
    *(float2*)(out + idx) = make_float2(s0, s1);
}

extern "C" void kernel_launch(void* const* d_in, const int* in_sizes, int n_in,
                              void* d_out, int out_size, void* d_ws, size_t ws_size,
                              hipStream_t stream) {
    (void)in_sizes; (void)n_in; (void)out_size; (void)ws_size;
    const float* x        = (const float*)d_in[0];
    const float* ada      = (const float*)d_in[1];
    const float* bup      = (const float*)d_in[2];
    const float* bdn      = (const float*)d_in[3];
    const float* ln_g     = (const float*)d_in[4];
    const float* ln_b     = (const float*)d_in[5];
    const float* W1       = (const float*)d_in[6];
    const float* b1       = (const float*)d_in[7];
    const float* W2       = (const float*)d_in[8];
    const float* b2       = (const float*)d_in[9];

    char* ws = (char*)d_ws;
    unsigned short* wbf = (unsigned short*)(ws + 0);         // 8 MiB
    unsigned short* P1b = (unsigned short*)(ws + 8388608);   // 4 MiB (16 bf16 slabs; gemm1 uses 8)
    unsigned short* P2b = (unsigned short*)(ws + 12582912);  // 2 MiB (8 bf16 slabs)
    unsigned short* cbf = (unsigned short*)(ws + 14680064);  // 256 KiB each
    unsigned short* xbf = (unsigned short*)(ws + 14942208);
    unsigned short* hbf = (unsigned short*)(ws + 15204352);
    unsigned short* ybf = (unsigned short*)(ws + 15466496);
    float* t1g          = (float*)(ws + 15728640);           // 4 KiB
    int* cnt1           = (int*)(ws + 15732736);             // 16 ints
    int* cnt4           = (int*)(ws + 15732800);             // 16 ints

    // 1. LN + bf16 casts (+ zero cnt1)
    ln_cast_kernel<<<128, 256, 0, stream>>>(ada, ln_g, ln_b, x, cbf, xbf, cnt1);
    // 2. GEMM1 + wide-tail hgen (z=0) and GEMM3 (z=1), one launch
    gemm13h_kernel<<<dim3(16, 8, 2), 256, 0, stream>>>(cbf, W1, P1b, xbf, bdn, P2b, b1, hbf, cnt1);
    // 3. GEMM2: wbf = bf16(hbf @ W2 + b2)
    gemm2_kernel<<<512, 256, 0, stream>>>(hbf, W2, b2, wbf);
    // 4. row epilogue: t2, y, ybf, t1 -> t1g (+ zero cnt4)
    e1big_kernel<<<128, 256, 0, stream>>>(P2b, wbf, x, ybf, t1g, cnt4);
    // 5. GEMM4 + wide-tail final accumulate
    gemm4f_kernel<<<dim3(16, 16), 256, 0, stream>>>(ybf, bup, P1b, wbf, t1g, x, (float*)d_out, cnt4);
}

// Round 13
// 53.629 us; speedup vs baseline: 1.8564x; 1.8564x over previous
//
#include <hip/hip_runtime.h>
#include <hip/hip_bf16.h>

// ---- problem constants: B=128, D=1024, ADA=1024, R=8, 4*D*R=32768 ----

typedef __attribute__((ext_vector_type(8))) __bf16 bf16x8;
typedef __attribute__((ext_vector_type(8))) short short8v;
typedef __attribute__((ext_vector_type(4))) float f32x4;

__device__ __forceinline__ float gelu_exact(float v) {
    return 0.5f * v * (1.0f + erff(v * 0.7071067811865476f));
}
__device__ __forceinline__ unsigned short f2bf(float f) {
    union { float f; unsigned u; } c; c.f = f;
    return (unsigned short)((c.u + 0x7FFFu + ((c.u >> 16) & 1u)) >> 16);
}
__device__ __forceinline__ float bf2f(unsigned short u) {
    union { float f; unsigned u32; } c; c.u32 = ((unsigned)u) << 16; return c.f;
}

// ---------- LayerNorm(ada_emb) -> c_bf16 ; cast x -> x_bf16 ----------
__global__ __launch_bounds__(256) void ln_cast_kernel(
    const float* __restrict__ ada, const float* __restrict__ g, const float* __restrict__ be,
    const float* __restrict__ x, unsigned short* __restrict__ cbf, unsigned short* __restrict__ xbf)
{
    int b = blockIdx.x, t = threadIdx.x;
    float4 v = ((const float4*)(ada + b * 1024))[t];
    float s  = v.x + v.y + v.z + v.w;
    float ss = v.x*v.x + v.y*v.y + v.z*v.z + v.w*v.w;
    #pragma unroll
    for (int off = 32; off; off >>= 1) { s += __shfl_xor(s, off); ss += __shfl_xor(ss, off); }
    __shared__ float rs[4], rss[4];
    int wid = t >> 6;
    if ((t & 63) == 0) { rs[wid] = s; rss[wid] = ss; }
    __syncthreads();
    float S  = rs[0] + rs[1] + rs[2] + rs[3];
    float SS = rss[0] + rss[1] + rss[2] + rss[3];
    float mu = S * (1.0f / 1024.0f);
    float rstd = rsqrtf(SS * (1.0f / 1024.0f) - mu * mu + 1e-5f);
    float4 gv = ((const float4*)g)[t];
    float4 bv = ((const float4*)be)[t];
    ushort4 o;
    o.x = f2bf((v.x - mu) * rstd * gv.x + bv.x);
    o.y = f2bf((v.y - mu) * rstd * gv.y + bv.y);
    o.z = f2bf((v.z - mu) * rstd * gv.z + bv.z);
    o.w = f2bf((v.w - mu) * rstd * gv.w + bv.w);
    ((ushort4*)(cbf + b * 1024))[t] = o;
    float4 xv = ((const float4*)(x + b * 1024))[t];
    ushort4 xo;
    xo.x = f2bf(xv.x); xo.y = f2bf(xv.y); xo.z = f2bf(xv.z); xo.w = f2bf(xv.w);
    ((ushort4*)(xbf + b * 1024))[t] = xo;
}

// ---------- MFMA GEMM body (round-3 staging/pipeline): C16 = bf16(A*B [+ bias]) ----------
// BT=false: B[k][n] row-major (ld=ldb).  BT=true: B[k][n] = Bsrc[n][k]
template <bool BT, bool BIAS>
__device__ __forceinline__ void gemm_body(
    const unsigned short* __restrict__ A, const float* __restrict__ Bm,
    unsigned short* __restrict__ C16, const float* __restrict__ bias,
    const int ldb, const int ldc, const int kchunk, const int k0base, const int n0)
{
    __shared__ __align__(16) unsigned short As[2][128 * 72];
    __shared__ __align__(16) unsigned short Bs[2][64 * 72];
    const int t = threadIdx.x;
    const int lane = t & 63, wid = t >> 6;
    const int wm = wid >> 1, wn = wid & 1;
    const int q = lane >> 4, c16 = lane & 15;

    const int arow = t >> 1, ahalf = t & 1;
    const unsigned short* aptr = A + arow * 1024 + k0base + ahalf * 32;
    const int adoff = arow * 72 + ahalf * 32;

    const int bnp = t & 31, bkc = t >> 5;   // !BT
    const int bnr = t >> 2, bpart = t & 3;  // BT
    const float* bptr = BT ? (Bm + (size_t)(n0 + bnr) * ldb + k0base + bpart * 16)
                           : (Bm + (size_t)(k0base + bkc * 8) * ldb + n0 + bnp * 2);

    f32x4 acc[4][2] = {};
    short8v ra0, ra1, ra2, ra3;
    float2 rb0, rb1, rb2, rb3, rb4, rb5, rb6, rb7;
    float4 rt0, rt1, rt2, rt3;

    auto LOAD = [&](int kk) {
        const int koff = kk << 6;
        const unsigned short* ap = aptr + koff;
        ra0 = *(const short8v*)(ap);      ra1 = *(const short8v*)(ap + 8);
        ra2 = *(const short8v*)(ap + 16); ra3 = *(const short8v*)(ap + 24);
        if (!BT) {
            const float* bp = bptr + (size_t)koff * ldb;
            rb0 = *(const float2*)(bp);                    rb1 = *(const float2*)(bp + (size_t)ldb);
            rb2 = *(const float2*)(bp + (size_t)2 * ldb);  rb3 = *(const float2*)(bp + (size_t)3 * ldb);
            rb4 = *(const float2*)(bp + (size_t)4 * ldb);  rb5 = *(const float2*)(bp + (size_t)5 * ldb);
            rb6 = *(const float2*)(bp + (size_t)6 * ldb);  rb7 = *(const float2*)(bp + (size_t)7 * ldb);
        } else {
            const float* bp = bptr + koff;
            rt0 = *(const float4*)(bp);     rt1 = *(const float4*)(bp + 4);
            rt2 = *(const float4*)(bp + 8); rt3 = *(const float4*)(bp + 12);
        }
    };
    auto STORE_LDS = [&](int buf) {
        unsigned short* ad = &As[buf][adoff];
        *(short8v*)(ad)      = ra0; *(short8v*)(ad + 8)  = ra1;
        *(short8v*)(ad + 16) = ra2; *(short8v*)(ad + 24) = ra3;
        if (!BT) {
            short8v s0, s1;
            s0[0]=(short)f2bf(rb0.x); s1[0]=(short)f2bf(rb0.y);
            s0[1]=(short)f2bf(rb1.x); s1[1]=(short)f2bf(rb1.y);
            s0[2]=(short)f2bf(rb2.x); s1[2]=(short)f2bf(rb2.y);
            s0[3]=(short)f2bf(rb3.x); s1[3]=(short)f2bf(rb3.y);
            s0[4]=(short)f2bf(rb4.x); s1[4]=(short)f2bf(rb4.y);
            s0[5]=(short)f2bf(rb5.x); s1[5]=(short)f2bf(rb5.y);
            s0[6]=(short)f2bf(rb6.x); s1[6]=(short)f2bf(rb6.y);
            s0[7]=(short)f2bf(rb7.x); s1[7]=(short)f2bf(rb7.y);
            *(short8v*)(&Bs[buf][(bnp * 2 + 0) * 72 + bkc * 8]) = s0;
            *(short8v*)(&Bs[buf][(bnp * 2 + 1) * 72 + bkc * 8]) = s1;
        } else {
            short8v s0, s1;
            s0[0]=(short)f2bf(rt0.x); s0[1]=(short)f2bf(rt0.y); s0[2]=(short)f2bf(rt0.z); s0[3]=(short)f2bf(rt0.w);
            s0[4]=(short)f2bf(rt1.x); s0[5]=(short)f2bf(rt1.y); s0[6]=(short)f2bf(rt1.z); s0[7]=(short)f2bf(rt1.w);
            s1[0]=(short)f2bf(rt2.x); s1[1]=(short)f2bf(rt2.y); s1[2]=(short)f2bf(rt2.z); s1[3]=(short)f2bf(rt2.w);
            s1[4]=(short)f2bf(rt3.x); s1[5]=(short)f2bf(rt3.y); s1[6]=(short)f2bf(rt3.z); s1[7]=(short)f2bf(rt3.w);
            *(short8v*)(&Bs[buf][bnr * 72 + bpart * 16])     = s0;
            *(short8v*)(&Bs[buf][bnr * 72 + bpart * 16 + 8]) = s1;
        }
    };

    const int nsteps = kchunk >> 6;
    LOAD(0);
    STORE_LDS(0);
    if (nsteps > 1) LOAD(1);
    __syncthreads();

    for (int kk = 0; kk < nsteps; ++kk) {
        if (kk + 1 < nsteps) STORE_LDS((kk + 1) & 1);
        if (kk + 2 < nsteps) LOAD(kk + 2);
        const unsigned short* Ab = &As[kk & 1][0];
        const unsigned short* Bb = &Bs[kk & 1][0];
        #pragma unroll
        for (int ks = 0; ks < 64; ks += 32) {
            bf16x8 af[4], bfv[2];
            #pragma unroll
            for (int mt = 0; mt < 4; ++mt)
                af[mt] = __builtin_bit_cast(bf16x8,
                    *(const short8v*)(Ab + (wm * 64 + mt * 16 + c16) * 72 + ks + q * 8));
            #pragma unroll
            for (int nt = 0; nt < 2; ++nt)
                bfv[nt] = __builtin_bit_cast(bf16x8,
                    *(const short8v*)(Bb + (wn * 32 + nt * 16 + c16) * 72 + ks + q * 8));
            #pragma unroll
            for (int mt = 0; mt < 4; ++mt)
                #pragma unroll
                for (int nt = 0; nt < 2; ++nt)
                    acc[mt][nt] = __builtin_amdgcn_mfma_f32_16x16x32_bf16(
                        af[mt], bfv[nt], acc[mt][nt], 0, 0, 0);
        }
        if (kk + 1 < nsteps) __syncthreads();
    }
    // store bf16 (D frag: col = lane&15, row = (lane>>4)*4 + j)
    #pragma unroll
    for (int mt = 0; mt < 4; ++mt) {
        const int m = wm * 64 + mt * 16 + q * 4;
        #pragma unroll
        for (int nt = 0; nt < 2; ++nt) {
            const int n = n0 + wn * 32 + nt * 16 + c16;
            const float bb = BIAS ? bias[n] : 0.0f;
            #pragma unroll
            for (int j = 0; j < 4; ++j)
                C16[(size_t)(m + j) * ldc + n] = f2bf(acc[mt][nt][j] + bb);
        }
    }
}

// GEMM1 (c@W1 -> P1b slabs) + GEMM3 (x@bdn -> P2b slabs), split-K 8, grid (16,8,2)
__global__ __launch_bounds__(256, 2) void gemm13_kernel(
    const unsigned short* __restrict__ cbf, const float* __restrict__ W1, unsigned short* __restrict__ P1b,
    const unsigned short* __restrict__ xbf, const float* __restrict__ bdn, unsigned short* __restrict__ P2b)
{
    const unsigned short* A = blockIdx.z ? xbf : cbf;
    const float* B = blockIdx.z ? bdn : W1;
    unsigned short* C = (blockIdx.z ? P2b : P1b) + blockIdx.y * 131072;
    gemm_body<false, false>(A, B, C, nullptr, 1024, 1024, 128, blockIdx.y * 128, blockIdx.x * 64);
}

// GEMM2: wbf = bf16(hbf @ W2 + b2), direct store, grid (512)
__global__ __launch_bounds__(256, 2) void gemm2_kernel(
    const unsigned short* __restrict__ hbf, const float* __restrict__ W2,
    const float* __restrict__ b2, unsigned short* __restrict__ wbf)
{
    gemm_body<false, true>(hbf, W2, wbf, b2, 32768, 32768, 1024, 0, blockIdx.x * 64);
}

// GEMM4: bf16 partials of y @ base_up^T, split-K 16, grid (16,16)
__global__ __launch_bounds__(256, 2) void gemm4_kernel(
    const unsigned short* __restrict__ ybf, const float* __restrict__ bup, unsigned short* __restrict__ P1b)
{
    gemm_body<true, false>(ybf, bup, P1b + blockIdx.y * 131072, nullptr,
                           1024, 1024, 64, blockIdx.y * 64, blockIdx.x * 64);
}

// ---------- h = bf16(gelu(sum bf16 partials + b1)), ushort2, 256 blocks ----------
__global__ __launch_bounds__(256) void hgen_kernel(
    const unsigned short* __restrict__ P1b, const float* __restrict__ bias,
    unsigned short* __restrict__ hbf)
{
    const int idx2 = blockIdx.x * 256 + threadIdx.x;   // ushort2 groups over 131072 elems
    float2 s = ((const float2*)bias)[idx2 & 511];
    #pragma unroll
    for (int p = 0; p < 8; ++p) {
        ushort2 v = ((const ushort2*)(P1b + p * 131072))[idx2];
        s.x += bf2f(v.x); s.y += bf2f(v.y);
    }
    ushort2 o;
    o.x = f2bf(gelu_exact(s.x));
    o.y = f2bf(gelu_exact(s.y));
    ((ushort2*)hbf)[idx2] = o;
}

// ---------- per-row epilogue, 2 blocks/row: t2 (redundant), half of {y, ybf, t1-partial} ----------
__device__ __forceinline__ void block_reduce8(float a[8], float* out8, float (*scr)[8], int t) {
    #pragma unroll
    for (int r = 0; r < 8; ++r)
        #pragma unroll
        for (int off = 32; off; off >>= 1)
            a[r] += __shfl_xor(a[r], off);
    if ((t & 63) == 0) {
        #pragma unroll
        for (int r = 0; r < 8; ++r) scr[t >> 6][r] = a[r];
    }
    __syncthreads();
    if (t < 8) out8[t] = scr[0][t] + scr[1][t] + scr[2][t] + scr[3][t];
    __syncthreads();
}

__global__ __launch_bounds__(256) void e1big_kernel(
    const unsigned short* __restrict__ P2b, const unsigned short* __restrict__ wbf,
    const float* __restrict__ x, unsigned short* __restrict__ ybf,
    float* __restrict__ t1g)
{
    __shared__ float scr[4][8];
    __shared__ float t2s[8], t1s[8];
    const int b = blockIdx.x >> 1, half = blockIdx.x & 1, t = threadIdx.x;
    const unsigned short* wrow = wbf + (size_t)b * 32768;
    const float* xrow = x + b * 1024;

    // stage 1 (redundant in both halves, identical order): t2[r] = sum_d la2[b,d,r]*x[b,d]
    float a[8] = {0,0,0,0,0,0,0,0};
    #pragma unroll
    for (int i = 0; i < 4; ++i) {
        int d = t + i * 256;
        float xv = xrow[d];
        short8v wv = *(const short8v*)(wrow + 16384 + d * 8);
        #pragma unroll
        for (int r = 0; r < 8; ++r) a[r] += xv * bf2f((unsigned short)wv[r]);
    }
    block_reduce8(a, t2s, scr, t);
    float t2v[8];
    #pragma unroll
    for (int r = 0; r < 8; ++r) t2v[r] = t2s[r];

    // stage 2 (this block's half of l): y = gelu(sum P2b + lb2@t2); t1-partial
    float a1[8] = {0,0,0,0,0,0,0,0};
    #pragma unroll
    for (int i = 0; i < 2; ++i) {
        int l = half * 512 + t + i * 256;
        float s = 0.0f;
        #pragma unroll
        for (int p = 0; p < 8; ++p) s += bf2f(P2b[p * 131072 + b * 1024 + l]);
        short8v w2v = *(const short8v*)(wrow + 24576 + l * 8);
        #pragma unroll
        for (int r = 0; r < 8; ++r) s += bf2f((unsigned short)w2v[r]) * t2v[r];
        float y = gelu_exact(s);
        ybf[b * 1024 + l] = f2bf(y);
        short8v w1v = *(const short8v*)(wrow + 8192 + l * 8);
        #pragma unroll
        for (int r = 0; r < 8; ++r) a1[r] += y * bf2f((unsigned short)w1v[r]);
    }
    block_reduce8(a1, t1s, scr, t);
    if (t < 8) t1g[b * 16 + half * 8 + t] = t1s[t];
}

// ---------- out = x + la1@t1 + sum GEMM4 bf16 partials (16 slabs), 512 blocks ----------
__global__ __launch_bounds__(256) void e2f_kernel(
    const unsigned short* __restrict__ P1b, const unsigned short* __restrict__ wbf,
    const float* __restrict__ t1g, const float* __restrict__ x, float* __restrict__ out)
{
    const int idx = blockIdx.x * 256 + threadIdx.x;   // 0..131071
    const int b = idx >> 10, k = idx & 1023;
    float s = x[idx];
    #pragma unroll
    for (int p = 0; p < 16; ++p) s += bf2f(P1b[p * 131072 + idx]);
    short8v w0 = *(const short8v*)(wbf + (size_t)b * 32768 + k * 8);
    #pragma unroll
    for (int r = 0; r < 8; ++r) {
        float t1v = t1g[b * 16 + r] + t1g[b * 16 + 8 + r];
        s += bf2f((unsigned short)w0[r]) * t1v;
    }
    out[idx] = s;
}

extern "C" void kernel_launch(void* const* d_in, const int* in_sizes, int n_in,
                              void* d_out, int out_size, void* d_ws, size_t ws_size,
                              hipStream_t stream) {
    (void)in_sizes; (void)n_in; (void)out_size; (void)ws_size;
    const float* x        = (const float*)d_in[0];
    const float* ada      = (const float*)d_in[1];
    const float* bup      = (const float*)d_in[2];
    const float* bdn      = (const float*)d_in[3];
    const float* ln_g     = (const float*)d_in[4];
    const float* ln_b     = (const float*)d_in[5];
    const float* W1       = (const float*)d_in[6];
    const float* b1       = (const float*)d_in[7];
    const float* W2       = (const float*)d_in[8];
    const float* b2       = (const float*)d_in[9];

    char* ws = (char*)d_ws;
    unsigned short* wbf = (unsigned short*)(ws + 0);         // 8 MiB
    unsigned short* P1b = (unsigned short*)(ws + 8388608);   // 4 MiB (16 bf16 slabs; gemm1 uses 8)
    unsigned short* P2b = (unsigned short*)(ws + 12582912);  // 2 MiB (8 bf16 slabs)
    unsigned short* cbf = (unsigned short*)(ws + 14680064);  // 256 KiB each
    unsigned short* xbf = (unsigned short*)(ws + 14942208);
    unsigned short* hbf = (unsigned short*)(ws + 15204352);
    unsigned short* ybf = (unsigned short*)(ws + 15466496);
    float* t1g          = (float*)(ws + 15728640);           // 8 KiB (128 rows x 2 partials x 8)

    // 1. LN + bf16 casts
    ln_cast_kernel<<<128, 256, 0, stream>>>(ada, ln_g, ln_b, x, cbf, xbf);
    // 2. GEMM1 (c@W1 -> P1b) + GEMM3 (x@bdn -> P2b), split-K 8, one launch
    gemm13_kernel<<<dim3(16, 8, 2), 256, 0, stream>>>(cbf, W1, P1b, xbf, bdn, P2b);
    // 3. hbf = bf16(gelu(sum P1b + b1)), 256 blocks
    hgen_kernel<<<256, 256, 0, stream>>>(P1b, b1, hbf);
    // 4. GEMM2: wbf = bf16(hbf @ W2 + b2)
    gemm2_kernel<<<512, 256, 0, stream>>>(hbf, W2, b2, wbf);
    // 5. row epilogue, 2 blocks/row: t2, y, ybf, t1-partials -> t1g
    e1big_kernel<<<256, 256, 0, stream>>>(P2b, wbf, x, ybf, t1g);
    // 6. GEMM4: bf16 partials of y @ bup^T -> P1b (split-K 16)
    gemm4_kernel<<<dim3(16, 16), 256, 0, stream>>>(ybf, bup, P1b);
    // 7. out = x + la1@t1 + sum partials
    e2f_kernel<<<512, 256, 0, stream>>>(P1b, wbf, t1g, x, (float*)d_out);
}

// Round 14
// 53.555 us; speedup vs baseline: 1.8590x; 1.0014x over previous
//
#include <hip/hip_runtime.h>
#include <hip/hip_bf16.h>

// ---- problem constants: B=128, D=1024, ADA=1024, R=8, 4*D*R=32768 ----

typedef __attribute__((ext_vector_type(8))) __bf16 bf16x8;
typedef __attribute__((ext_vector_type(8))) short short8v;
typedef __attribute__((ext_vector_type(4))) float f32x4;

__device__ __forceinline__ float gelu_exact(float v) {
    return 0.5f * v * (1.0f + erff(v * 0.7071067811865476f));
}
__device__ __forceinline__ unsigned short f2bf(float f) {
    union { float f; unsigned u; } c; c.f = f;
    return (unsigned short)((c.u + 0x7FFFu + ((c.u >> 16) & 1u)) >> 16);
}
__device__ __forceinline__ float bf2f(unsigned short u) {
    union { float f; unsigned u32; } c; c.u32 = ((unsigned)u) << 16; return c.f;
}

// ---------- LayerNorm(ada_emb) -> c_bf16 ; cast x -> x_bf16 ----------
__global__ __launch_bounds__(256) void ln_cast_kernel(
    const float* __restrict__ ada, const float* __restrict__ g, const float* __restrict__ be,
    const float* __restrict__ x, unsigned short* __restrict__ cbf, unsigned short* __restrict__ xbf)
{
    int b = blockIdx.x, t = threadIdx.x;
    float4 v = ((const float4*)(ada + b * 1024))[t];
    float s  = v.x + v.y + v.z + v.w;
    float ss = v.x*v.x + v.y*v.y + v.z*v.z + v.w*v.w;
    #pragma unroll
    for (int off = 32; off; off >>= 1) { s += __shfl_xor(s, off); ss += __shfl_xor(ss, off); }
    __shared__ float rs[4], rss[4];
    int wid = t >> 6;
    if ((t & 63) == 0) { rs[wid] = s; rss[wid] = ss; }
    __syncthreads();
    float S  = rs[0] + rs[1] + rs[2] + rs[3];
    float SS = rss[0] + rss[1] + rss[2] + rss[3];
    float mu = S * (1.0f / 1024.0f);
    float rstd = rsqrtf(SS * (1.0f / 1024.0f) - mu * mu + 1e-5f);
    float4 gv = ((const float4*)g)[t];
    float4 bv = ((const float4*)be)[t];
    ushort4 o;
    o.x = f2bf((v.x - mu) * rstd * gv.x + bv.x);
    o.y = f2bf((v.y - mu) * rstd * gv.y + bv.y);
    o.z = f2bf((v.z - mu) * rstd * gv.z + bv.z);
    o.w = f2bf((v.w - mu) * rstd * gv.w + bv.w);
    ((ushort4*)(cbf + b * 1024))[t] = o;
    float4 xv = ((const float4*)(x + b * 1024))[t];
    ushort4 xo;
    xo.x = f2bf(xv.x); xo.y = f2bf(xv.y); xo.z = f2bf(xv.z); xo.w = f2bf(xv.w);
    ((ushort4*)(xbf + b * 1024))[t] = xo;
}

// ---------- MFMA GEMM body (round-3 staging/pipeline): C16 = bf16(A*B [+ bias]) ----------
// BT=false: B[k][n] row-major (ld=ldb).  BT=true: B[k][n] = Bsrc[n][k]
template <bool BT, bool BIAS>
__device__ __forceinline__ void gemm_body(
    const unsigned short* __restrict__ A, const float* __restrict__ Bm,
    unsigned short* __restrict__ C16, const float* __restrict__ bias,
    const int ldb, const int ldc, const int kchunk, const int k0base, const int n0)
{
    __shared__ __align__(16) unsigned short As[2][128 * 72];
    __shared__ __align__(16) unsigned short Bs[2][64 * 72];
    const int t = threadIdx.x;
    const int lane = t & 63, wid = t >> 6;
    const int wm = wid >> 1, wn = wid & 1;
    const int q = lane >> 4, c16 = lane & 15;

    const int arow = t >> 1, ahalf = t & 1;
    const unsigned short* aptr = A + arow * 1024 + k0base + ahalf * 32;
    const int adoff = arow * 72 + ahalf * 32;

    const int bnp = t & 31, bkc = t >> 5;   // !BT
    const int bnr = t >> 2, bpart = t & 3;  // BT
    const float* bptr = BT ? (Bm + (size_t)(n0 + bnr) * ldb + k0base + bpart * 16)
                           : (Bm + (size_t)(k0base + bkc * 8) * ldb + n0 + bnp * 2);

    f32x4 acc[4][2] = {};
    short8v ra0, ra1, ra2, ra3;
    float2 rb0, rb1, rb2, rb3, rb4, rb5, rb6, rb7;
    float4 rt0, rt1, rt2, rt3;

    auto LOAD = [&](int kk) {
        const int koff = kk << 6;
        const unsigned short* ap = aptr + koff;
        ra0 = *(const short8v*)(ap);      ra1 = *(const short8v*)(ap + 8);
        ra2 = *(const short8v*)(ap + 16); ra3 = *(const short8v*)(ap + 24);
        if (!BT) {
            const float* bp = bptr + (size_t)koff * ldb;
            rb0 = *(const float2*)(bp);                    rb1 = *(const float2*)(bp + (size_t)ldb);
            rb2 = *(const float2*)(bp + (size_t)2 * ldb);  rb3 = *(const float2*)(bp + (size_t)3 * ldb);
            rb4 = *(const float2*)(bp + (size_t)4 * ldb);  rb5 = *(const float2*)(bp + (size_t)5 * ldb);
            rb6 = *(const float2*)(bp + (size_t)6 * ldb);  rb7 = *(const float2*)(bp + (size_t)7 * ldb);
        } else {
            const float* bp = bptr + koff;
            rt0 = *(const float4*)(bp);     rt1 = *(const float4*)(bp + 4);
            rt2 = *(const float4*)(bp + 8); rt3 = *(const float4*)(bp + 12);
        }
    };
    auto STORE_LDS = [&](int buf) {
        unsigned short* ad = &As[buf][adoff];
        *(short8v*)(ad)      = ra0; *(short8v*)(ad + 8)  = ra1;
        *(short8v*)(ad + 16) = ra2; *(short8v*)(ad + 24) = ra3;
        if (!BT) {
            short8v s0, s1;
            s0[0]=(short)f2bf(rb0.x); s1[0]=(short)f2bf(rb0.y);
            s0[1]=(short)f2bf(rb1.x); s1[1]=(short)f2bf(rb1.y);
            s0[2]=(short)f2bf(rb2.x); s1[2]=(short)f2bf(rb2.y);
            s0[3]=(short)f2bf(rb3.x); s1[3]=(short)f2bf(rb3.y);
            s0[4]=(short)f2bf(rb4.x); s1[4]=(short)f2bf(rb4.y);
            s0[5]=(short)f2bf(rb5.x); s1[5]=(short)f2bf(rb5.y);
            s0[6]=(short)f2bf(rb6.x); s1[6]=(short)f2bf(rb6.y);
            s0[7]=(short)f2bf(rb7.x); s1[7]=(short)f2bf(rb7.y);
            *(short8v*)(&Bs[buf][(bnp * 2 + 0) * 72 + bkc * 8]) = s0;
            *(short8v*)(&Bs[buf][(bnp * 2 + 1) * 72 + bkc * 8]) = s1;
        } else {
            short8v s0, s1;
            s0[0]=(short)f2bf(rt0.x); s0[1]=(short)f2bf(rt0.y); s0[2]=(short)f2bf(rt0.z); s0[3]=(short)f2bf(rt0.w);
            s0[4]=(short)f2bf(rt1.x); s0[5]=(short)f2bf(rt1.y); s0[6]=(short)f2bf(rt1.z); s0[7]=(short)f2bf(rt1.w);
            s1[0]=(short)f2bf(rt2.x); s1[1]=(short)f2bf(rt2.y); s1[2]=(short)f2bf(rt2.z); s1[3]=(short)f2bf(rt2.w);
            s1[4]=(short)f2bf(rt3.x); s1[5]=(short)f2bf(rt3.y); s1[6]=(short)f2bf(rt3.z); s1[7]=(short)f2bf(rt3.w);
            *(short8v*)(&Bs[buf][bnr * 72 + bpart * 16])     = s0;
            *(short8v*)(&Bs[buf][bnr * 72 + bpart * 16 + 8]) = s1;
        }
    };

    const int nsteps = kchunk >> 6;
    LOAD(0);
    STORE_LDS(0);
    if (nsteps > 1) LOAD(1);
    __syncthreads();

    for (int kk = 0; kk < nsteps; ++kk) {
        if (kk + 1 < nsteps) STORE_LDS((kk + 1) & 1);
        if (kk + 2 < nsteps) LOAD(kk + 2);
        const unsigned short* Ab = &As[kk & 1][0];
        const unsigned short* Bb = &Bs[kk & 1][0];
        #pragma unroll
        for (int ks = 0; ks < 64; ks += 32) {
            bf16x8 af[4], bfv[2];
            #pragma unroll
            for (int mt = 0; mt < 4; ++mt)
                af[mt] = __builtin_bit_cast(bf16x8,
                    *(const short8v*)(Ab + (wm * 64 + mt * 16 + c16) * 72 + ks + q * 8));
            #pragma unroll
            for (int nt = 0; nt < 2; ++nt)
                bfv[nt] = __builtin_bit_cast(bf16x8,
                    *(const short8v*)(Bb + (wn * 32 + nt * 16 + c16) * 72 + ks + q * 8));
            #pragma unroll
            for (int mt = 0; mt < 4; ++mt)
                #pragma unroll
                for (int nt = 0; nt < 2; ++nt)
                    acc[mt][nt] = __builtin_amdgcn_mfma_f32_16x16x32_bf16(
                        af[mt], bfv[nt], acc[mt][nt], 0, 0, 0);
        }
        if (kk + 1 < nsteps) __syncthreads();
    }
    // store bf16 (D frag: col = lane&15, row = (lane>>4)*4 + j)
    #pragma unroll
    for (int mt = 0; mt < 4; ++mt) {
        const int m = wm * 64 + mt * 16 + q * 4;
        #pragma unroll
        for (int nt = 0; nt < 2; ++nt) {
            const int n = n0 + wn * 32 + nt * 16 + c16;
            const float bb = BIAS ? bias[n] : 0.0f;
            #pragma unroll
            for (int j = 0; j < 4; ++j)
                C16[(size_t)(m + j) * ldc + n] = f2bf(acc[mt][nt][j] + bb);
        }
    }
}

// GEMM1 (c@W1 -> P1b slabs) + GEMM3 (x@bdn -> P2b slabs), split-K 8, grid (16,8,2)
__global__ __launch_bounds__(256, 2) void gemm13_kernel(
    const unsigned short* __restrict__ cbf, const float* __restrict__ W1, unsigned short* __restrict__ P1b,
    const unsigned short* __restrict__ xbf, const float* __restrict__ bdn, unsigned short* __restrict__ P2b)
{
    const unsigned short* A = blockIdx.z ? xbf : cbf;
    const float* B = blockIdx.z ? bdn : W1;
    unsigned short* C = (blockIdx.z ? P2b : P1b) + blockIdx.y * 131072;
    gemm_body<false, false>(A, B, C, nullptr, 1024, 1024, 128, blockIdx.y * 128, blockIdx.x * 64);
}

// GEMM2: wbf = bf16(hbf @ W2 + b2), direct store, grid (512)
__global__ __launch_bounds__(256, 2) void gemm2_kernel(
    const unsigned short* __restrict__ hbf, const float* __restrict__ W2,
    const float* __restrict__ b2, unsigned short* __restrict__ wbf)
{
    gemm_body<false, true>(hbf, W2, wbf, b2, 32768, 32768, 1024, 0, blockIdx.x * 64);
}

// GEMM4: bf16 partials of y @ base_up^T, split-K 8, grid (16,8)
__global__ __launch_bounds__(256, 2) void gemm4_kernel(
    const unsigned short* __restrict__ ybf, const float* __restrict__ bup, unsigned short* __restrict__ P1b)
{
    gemm_body<true, false>(ybf, bup, P1b + blockIdx.y * 131072, nullptr,
                           1024, 1024, 128, blockIdx.y * 128, blockIdx.x * 64);
}

// ---------- h = bf16(gelu(sum bf16 partials + b1)), ushort2, 256 blocks ----------
__global__ __launch_bounds__(256) void hgen_kernel(
    const unsigned short* __restrict__ P1b, const float* __restrict__ bias,
    unsigned short* __restrict__ hbf)
{
    const int idx2 = blockIdx.x * 256 + threadIdx.x;   // ushort2 groups over 131072 elems
    float2 s = ((const float2*)bias)[idx2 & 511];
    #pragma unroll
    for (int p = 0; p < 8; ++p) {
        ushort2 v = ((const ushort2*)(P1b + p * 131072))[idx2];
        s.x += bf2f(v.x); s.y += bf2f(v.y);
    }
    ushort2 o;
    o.x = f2bf(gelu_exact(s.x));
    o.y = f2bf(gelu_exact(s.y));
    ((ushort2*)hbf)[idx2] = o;
}

// ---------- per-row epilogue, 2 blocks/row: t2 (redundant), half of {y, ybf, t1-partial} ----------
__device__ __forceinline__ void block_reduce8(float a[8], float* out8, float (*scr)[8], int t) {
    #pragma unroll
    for (int r = 0; r < 8; ++r)
        #pragma unroll
        for (int off = 32; off; off >>= 1)
            a[r] += __shfl_xor(a[r], off);
    if ((t & 63) == 0) {
        #pragma unroll
        for (int r = 0; r < 8; ++r) scr[t >> 6][r] = a[r];
    }
    __syncthreads();
    if (t < 8) out8[t] = scr[0][t] + scr[1][t] + scr[2][t] + scr[3][t];
    __syncthreads();
}

__global__ __launch_bounds__(256) void e1big_kernel(
    const unsigned short* __restrict__ P2b, const unsigned short* __restrict__ wbf,
    const float* __restrict__ x, unsigned short* __restrict__ ybf,
    float* __restrict__ t1g)
{
    __shared__ float scr[4][8];
    __shared__ float t2s[8], t1s[8];
    const int b = blockIdx.x >> 1, half = blockIdx.x & 1, t = threadIdx.x;
    const unsigned short* wrow = wbf + (size_t)b * 32768;
    const float* xrow = x + b * 1024;

    // stage 1 (redundant in both halves, identical order): t2[r] = sum_d la2[b,d,r]*x[b,d]
    float a[8] = {0,0,0,0,0,0,0,0};
    #pragma unroll
    for (int i = 0; i < 4; ++i) {
        int d = t + i * 256;
        float xv = xrow[d];
        short8v wv = *(const short8v*)(wrow + 16384 + d * 8);
        #pragma unroll
        for (int r = 0; r < 8; ++r) a[r] += xv * bf2f((unsigned short)wv[r]);
    }
    block_reduce8(a, t2s, scr, t);
    float t2v[8];
    #pragma unroll
    for (int r = 0; r < 8; ++r) t2v[r] = t2s[r];

    // stage 2 (this block's half of l, 2 consecutive l per thread):
    // y = gelu(sum P2b + lb2@t2); t1-partial
    float a1[8] = {0,0,0,0,0,0,0,0};
    {
        const int l = half * 512 + t * 2;
        float s0 = 0.0f, s1 = 0.0f;
        #pragma unroll
        for (int p = 0; p < 8; ++p) {
            ushort2 v = *(const ushort2*)(P2b + p * 131072 + b * 1024 + l);
            s0 += bf2f(v.x); s1 += bf2f(v.y);
        }
        short8v w2a = *(const short8v*)(wrow + 24576 + l * 8);
        short8v w2b = *(const short8v*)(wrow + 24576 + l * 8 + 8);
        #pragma unroll
        for (int r = 0; r < 8; ++r) {
            s0 += bf2f((unsigned short)w2a[r]) * t2v[r];
            s1 += bf2f((unsigned short)w2b[r]) * t2v[r];
        }
        float y0 = gelu_exact(s0), y1 = gelu_exact(s1);
        ushort2 yo; yo.x = f2bf(y0); yo.y = f2bf(y1);
        *(ushort2*)(ybf + b * 1024 + l) = yo;
        short8v w1a = *(const short8v*)(wrow + 8192 + l * 8);
        short8v w1b = *(const short8v*)(wrow + 8192 + l * 8 + 8);
        #pragma unroll
        for (int r = 0; r < 8; ++r)
            a1[r] += y0 * bf2f((unsigned short)w1a[r]) + y1 * bf2f((unsigned short)w1b[r]);
    }
    block_reduce8(a1, t1s, scr, t);
    if (t < 8) t1g[b * 16 + half * 8 + t] = t1s[t];
}

// ---------- out = x + la1@t1 + sum GEMM4 bf16 partials (8 slabs), 256 blocks, 2/thread ----------
__global__ __launch_bounds__(256) void e2f_kernel(
    const unsigned short* __restrict__ P1b, const unsigned short* __restrict__ wbf,
    const float* __restrict__ t1g, const float* __restrict__ x, float* __restrict__ out)
{
    const int i2 = blockIdx.x * 256 + threadIdx.x;   // pair index 0..65535
    const int idx = i2 * 2;
    const int b = idx >> 10, k = idx & 1023;
    float2 xv = *(const float2*)(x + idx);
    float s0 = xv.x, s1 = xv.y;
    #pragma unroll
    for (int p = 0; p < 8; ++p) {
        ushort2 v = *(const ushort2*)(P1b + p * 131072 + idx);
        s0 += bf2f(v.x); s1 += bf2f(v.y);
    }
    short8v w0 = *(const short8v*)(wbf + (size_t)b * 32768 + k * 8);
    short8v w1 = *(const short8v*)(wbf + (size_t)b * 32768 + k * 8 + 8);
    #pragma unroll
    for (int r = 0; r < 8; ++r) {
        float t1v = t1g[b * 16 + r] + t1g[b * 16 + 8 + r];
        s0 += bf2f((unsigned short)w0[r]) * t1v;
        s1 += bf2f((unsigned short)w1[r]) * t1v;
    }
    *(float2*)(out + idx) = make_float2(s0, s1);
}

extern "C" void kernel_launch(void* const* d_in, const int* in_sizes, int n_in,
                              void* d_out, int out_size, void* d_ws, size_t ws_size,
                              hipStream_t stream) {
    (void)in_sizes; (void)n_in; (void)out_size; (void)ws_size;
    const float* x        = (const float*)d_in[0];
    const float* ada      = (const float*)d_in[1];
    const float* bup      = (const float*)d_in[2];
    const float* bdn      = (const float*)d_in[3];
    const float* ln_g     = (const float*)d_in[4];
    const float* ln_b     = (const float*)d_in[5];
    const float* W1       = (const float*)d_in[6];
    const float* b1       = (const float*)d_in[7];
    const float* W2       = (const float*)d_in[8];
    const float* b2       = (const float*)d_in[9];

    char* ws = (char*)d_ws;
    unsigned short* wbf = (unsigned short*)(ws + 0);         // 8 MiB
    unsigned short* P1b = (unsigned short*)(ws + 8388608);   // 2 MiB (8 bf16 slabs, reused by gemm4)
    unsigned short* P2b = (unsigned short*)(ws + 10485760);  // 2 MiB (8 bf16 slabs)
    unsigned short* cbf = (unsigned short*)(ws + 12582912);  // 256 KiB each
    unsigned short* xbf = (unsigned short*)(ws + 12845056);
    unsigned short* hbf = (unsigned short*)(ws + 13107200);
    unsigned short* ybf = (unsigned short*)(ws + 13369344);
    float* t1g          = (float*)(ws + 13631488);           // 8 KiB (128 rows x 2 partials x 8)

    // 1. LN + bf16 casts
    ln_cast_kernel<<<128, 256, 0, stream>>>(ada, ln_g, ln_b, x, cbf, xbf);
    // 2. GEMM1 (c@W1 -> P1b) + GEMM3 (x@bdn -> P2b), split-K 8, one launch
    gemm13_kernel<<<dim3(16, 8, 2), 256, 0, stream>>>(cbf, W1, P1b, xbf, bdn, P2b);
    // 3. hbf = bf16(gelu(sum P1b + b1)), 256 blocks
    hgen_kernel<<<256, 256, 0, stream>>>(P1b, b1, hbf);
    // 4. GEMM2: wbf = bf16(hbf @ W2 + b2)
    gemm2_kernel<<<512, 256, 0, stream>>>(hbf, W2, b2, wbf);
    // 5. row epilogue, 2 blocks/row: t2, y, ybf, t1-partials -> t1g
    e1big_kernel<<<256, 256, 0, stream>>>(P2b, wbf, x, ybf, t1g);
    // 6. GEMM4: bf16 partials of y @ bup^T -> P1b (split-K 8)
    gemm4_kernel<<<dim3(16, 8), 256, 0, stream>>>(ybf, bup, P1b);
    // 7. out = x + la1@t1 + sum partials
    e2f_kernel<<<256, 256, 0, stream>>>(P1b, wbf, t1g, x, (float*)d_out);
}